// Round 3
// baseline (396.779 us; speedup 1.0000x reference)
//
#include <hip/hip_runtime.h>

#define BN_EPS 1e-3f

// ---------------------------------------------------------------------------
// Submanifold 3x3x3 conv, K-split 2-way: block = 256 threads = 128 voxels x
// 2 k-halves (waves 0,1: k 0..13; waves 2,3: k 14..26). Each thread: 16 fp32
// accumulators; weights read with wave-uniform indices (scalar loads).
// Whole-wave-empty taps are skipped via ballot. Partials combined via LDS.
// APPLY_BN: BN+ReLU of the PREVIOUS layer applied to gathered rows (scale /
// shift computed inline from raw stats). Output y is pre-BN.
// ---------------------------------------------------------------------------
template<bool APPLY_BN>
__global__ __launch_bounds__(256)
void subm_conv_kernel(const float* __restrict__ x,      // [N,16]
                      const float* __restrict__ W,      // [27,16,16] (k,c,o)
                      const int*   __restrict__ nbr,    // [N,27], -1 = missing
                      const float* __restrict__ stats,  // [32] prev sum|sumsq
                      const float* __restrict__ g,
                      const float* __restrict__ b,
                      float invN,
                      float* __restrict__ y,            // [N,16] pre-BN
                      int N)
{
    __shared__ float part[128 * 16];

    int lt   = threadIdx.x & 127;
    int half = threadIdx.x >> 7;          // wave-uniform (waves 0,1 vs 2,3)
    int v    = blockIdx.x * 128 + lt;
    bool active = v < N;

    float sc[16], sh[16];
    if (APPLY_BN) {
#pragma unroll
        for (int c = 0; c < 16; ++c) {
            float mu  = stats[c] * invN;
            float var = stats[16 + c] * invN - mu * mu;
            float s   = g[c] * rsqrtf(var + BN_EPS);
            sc[c] = s;
            sh[c] = b[c] - mu * s;
        }
    }

    float acc[16];
#pragma unroll
    for (int o = 0; o < 16; ++o) acc[o] = 0.f;

    int k0 = half ? 14 : 0;
    const int* nr = nbr + (size_t)v * 27;
    int idx[14];
#pragma unroll
    for (int j = 0; j < 14; ++j) {
        int k = k0 + j;
        idx[j] = (active && k < 27) ? nr[k] : -1;
    }

#pragma unroll 1
    for (int j = 0; j < 14; ++j) {
        int id = idx[j];
        if (__ballot(id >= 0) == 0ull) continue;   // whole wave empty -> skip
        float mm = id >= 0 ? 1.f : 0.f;
        int   ic = id >= 0 ? id : 0;
        const float4* xr = (const float4*)(x + (size_t)ic * 16);
        float4 r0 = xr[0], r1 = xr[1], r2 = xr[2], r3 = xr[3];
        float xv[16];
        *(float4*)(xv + 0)  = r0; *(float4*)(xv + 4)  = r1;
        *(float4*)(xv + 8)  = r2; *(float4*)(xv + 12) = r3;
        if (APPLY_BN) {
#pragma unroll
            for (int c = 0; c < 16; ++c)
                xv[c] = fmaxf(fmaf(xv[c], sc[c], sh[c]), 0.f);
        }
#pragma unroll
        for (int c = 0; c < 16; ++c) xv[c] *= mm;   // mask AFTER BN (zero pad row)

        const float* wk = W + (k0 + j) * 256;       // wave-uniform -> s_load
#pragma unroll
        for (int c = 0; c < 16; ++c) {
            float xc = xv[c];
            const float* wr = wk + c * 16;
#pragma unroll
            for (int o = 0; o < 16; ++o)
                acc[o] = fmaf(xc, wr[o], acc[o]);
        }
    }

    // combine the two k-halves
    if (half) {
        float4* p = (float4*)(part + lt * 16);
        p[0] = make_float4(acc[0],  acc[1],  acc[2],  acc[3]);
        p[1] = make_float4(acc[4],  acc[5],  acc[6],  acc[7]);
        p[2] = make_float4(acc[8],  acc[9],  acc[10], acc[11]);
        p[3] = make_float4(acc[12], acc[13], acc[14], acc[15]);
    }
    __syncthreads();
    if (!half && active) {
        const float4* p = (const float4*)(part + lt * 16);
        float4 p0 = p[0], p1 = p[1], p2 = p[2], p3 = p[3];
        float4* yo = (float4*)(y + (size_t)v * 16);
        yo[0] = make_float4(acc[0]  + p0.x, acc[1]  + p0.y, acc[2]  + p0.z, acc[3]  + p0.w);
        yo[1] = make_float4(acc[4]  + p1.x, acc[5]  + p1.y, acc[6]  + p1.z, acc[7]  + p1.w);
        yo[2] = make_float4(acc[8]  + p2.x, acc[9]  + p2.y, acc[10] + p2.z, acc[11] + p2.w);
        yo[3] = make_float4(acc[12] + p3.x, acc[13] + p3.y, acc[14] + p3.z, acc[15] + p3.w);
    }
}

// ---------------------------------------------------------------------------
// Per-channel sum / sumsq over y [N,16] (float4 grid-stride, channel group
// f&3 invariant per thread), wave shuffle-reduce, 32 atomics per block.
// ---------------------------------------------------------------------------
__global__ __launch_bounds__(256)
void stats_kernel(const float* __restrict__ y, float* __restrict__ stats, int n4)
{
    __shared__ float red[4][32];
    int tid = blockIdx.x * 256 + threadIdx.x;
    int T = gridDim.x * 256;
    float4 s = make_float4(0.f, 0.f, 0.f, 0.f);
    float4 q = make_float4(0.f, 0.f, 0.f, 0.f);
    for (int f = tid; f < n4; f += T) {
        float4 v = ((const float4*)y)[f];
        s.x += v.x; s.y += v.y; s.z += v.z; s.w += v.w;
        q.x += v.x * v.x; q.y += v.y * v.y; q.z += v.z * v.z; q.w += v.w * v.w;
    }
#pragma unroll
    for (int off = 4; off <= 32; off <<= 1) {
        s.x += __shfl_down(s.x, off); s.y += __shfl_down(s.y, off);
        s.z += __shfl_down(s.z, off); s.w += __shfl_down(s.w, off);
        q.x += __shfl_down(q.x, off); q.y += __shfl_down(q.y, off);
        q.z += __shfl_down(q.z, off); q.w += __shfl_down(q.w, off);
    }
    int lane = threadIdx.x & 63, wv = threadIdx.x >> 6;
    if (lane < 4) {
        int c = lane * 4;
        red[wv][c + 0] = s.x; red[wv][c + 1] = s.y; red[wv][c + 2] = s.z; red[wv][c + 3] = s.w;
        red[wv][16 + c + 0] = q.x; red[wv][16 + c + 1] = q.y;
        red[wv][16 + c + 2] = q.z; red[wv][16 + c + 3] = q.w;
    }
    __syncthreads();
    if (threadIdx.x < 32) {
        float v = red[0][threadIdx.x] + red[1][threadIdx.x] +
                  red[2][threadIdx.x] + red[3][threadIdx.x];
        atomicAdd(&stats[threadIdx.x], v);
    }
}

// First tensor: relu(bn1(y1)) -> plain stores (seg[0:N] strictly increasing
// => injective). BN scale/shift computed inline from raw stats (uniform).
__global__ __launch_bounds__(256)
void scatter_h_kernel(const float* __restrict__ y1, const float* __restrict__ stats,
                      const float* __restrict__ g, const float* __restrict__ b,
                      float invN, const int* __restrict__ seg,
                      float* __restrict__ merged, int N)
{
    int r = blockIdx.x * 256 + threadIdx.x;
    if (r >= N) return;
    float sc[16], sh[16];
#pragma unroll
    for (int c = 0; c < 16; ++c) {
        float mu  = stats[c] * invN;
        float var = stats[16 + c] * invN - mu * mu;
        float s   = g[c] * rsqrtf(var + BN_EPS);
        sc[c] = s;
        sh[c] = b[c] - mu * s;
    }
    const float4* yr = (const float4*)(y1 + (size_t)r * 16);
    float4* mo = (float4*)(merged + (size_t)seg[r] * 16);
#pragma unroll
    for (int i = 0; i < 4; ++i) {
        float4 v = yr[i];
        float4 rr;
        rr.x = fmaxf(fmaf(v.x, sc[i * 4 + 0], sh[i * 4 + 0]), 0.f);
        rr.y = fmaxf(fmaf(v.y, sc[i * 4 + 1], sh[i * 4 + 1]), 0.f);
        rr.z = fmaxf(fmaf(v.z, sc[i * 4 + 2], sh[i * 4 + 2]), 0.f);
        rr.w = fmaxf(fmaf(v.w, sc[i * 4 + 3], sh[i * 4 + 3]), 0.f);
        mo[i] = rr;
    }
}

__device__ __forceinline__ void obo_row(const float* __restrict__ feat2,
                                        const float* __restrict__ Wobo,
                                        int r, float v[16])
{
    const float4* fr = (const float4*)(feat2 + (size_t)r * 16);
    float fv[16];
    *(float4*)(fv + 0)  = fr[0]; *(float4*)(fv + 4)  = fr[1];
    *(float4*)(fv + 8)  = fr[2]; *(float4*)(fv + 12) = fr[3];
#pragma unroll
    for (int c = 0; c < 16; ++c) {
        float xc = fv[c];
        const float* wr = Wobo + c * 16;   // wave-uniform -> s_load
#pragma unroll
        for (int o = 0; o < 16; ++o) v[o] = fmaf(xc, wr[o], v[o]);
    }
}

// Second tensor: seg[N:2N] is NON-DECREASING (construction: within each
// (b,z,y) group x strictly increases; +1 on alternate rows with clamp keeps
// order), so equal slots form adjacent runs. The run leader sums the run and
// does a plain load-add-store into merged. NO atomics.
__global__ __launch_bounds__(256)
void scatter_t2_kernel(const float* __restrict__ feat2, const float* __restrict__ Wobo,
                       const float* __restrict__ bobo, const int* __restrict__ seg,
                       float* __restrict__ merged, int N)
{
    int r = blockIdx.x * 256 + threadIdx.x;
    if (r >= N) return;
    const int* seg2 = seg + N;
    int s = seg2[r];
    if (r > 0 && seg2[r - 1] == s) return;   // not the run leader
    float v[16];
#pragma unroll
    for (int o = 0; o < 16; ++o) v[o] = bobo[o];
    obo_row(feat2, Wobo, r, v);
    for (int i = r + 1; i < N && seg2[i] == s; ++i)
        obo_row(feat2, Wobo, i, v);
    float* mo = merged + (size_t)s * 16;
    float4* mo4 = (float4*)mo;
    float4 m0 = mo4[0], m1 = mo4[1], m2 = mo4[2], m3 = mo4[3];
    mo4[0] = make_float4(m0.x + v[0],  m0.y + v[1],  m0.z + v[2],  m0.w + v[3]);
    mo4[1] = make_float4(m1.x + v[4],  m1.y + v[5],  m1.z + v[6],  m1.w + v[7]);
    mo4[2] = make_float4(m2.x + v[8],  m2.y + v[9],  m2.z + v[10], m2.w + v[11]);
    mo4[3] = make_float4(m3.x + v[12], m3.y + v[13], m3.z + v[14], m3.w + v[15]);
}

// out[u,:] = merged[u,:16] @ Wf + bf. Thread (j, rowhalf) keeps Wf[:,j] in
// registers, loops 128 rows; merged loads wave-uniform, stores coalesced.
__global__ __launch_bounds__(256)
void final_gemm_kernel(const float* __restrict__ merged, const float* __restrict__ Wf,
                       const float* __restrict__ bf, float* __restrict__ out, int U)
{
    int j  = threadIdx.x & 127;
    int rh = threadIdx.x >> 7;
    int u0 = blockIdx.x * 256 + rh * 128;
    if (u0 >= U) return;
    float wj[16];
#pragma unroll
    for (int c = 0; c < 16; ++c) wj[c] = Wf[c * 128 + j];
    float bj = bf[j];
    int rend = min(u0 + 128, U);

    const float4* mr = (const float4*)(merged + (size_t)u0 * 16);
    float4 a0 = mr[0], a1 = mr[1], a2 = mr[2], a3 = mr[3];
#pragma unroll 1
    for (int u = u0; u < rend; ++u) {
        float4 c0 = a0, c1 = a1, c2 = a2, c3 = a3;
        if (u + 1 < rend) {
            const float4* nx = (const float4*)(merged + (size_t)(u + 1) * 16);
            a0 = nx[0]; a1 = nx[1]; a2 = nx[2]; a3 = nx[3];
        }
        float s = bj;
        s = fmaf(c0.x, wj[0],  s); s = fmaf(c0.y, wj[1],  s);
        s = fmaf(c0.z, wj[2],  s); s = fmaf(c0.w, wj[3],  s);
        s = fmaf(c1.x, wj[4],  s); s = fmaf(c1.y, wj[5],  s);
        s = fmaf(c1.z, wj[6],  s); s = fmaf(c1.w, wj[7],  s);
        s = fmaf(c2.x, wj[8],  s); s = fmaf(c2.y, wj[9],  s);
        s = fmaf(c2.z, wj[10], s); s = fmaf(c2.w, wj[11], s);
        s = fmaf(c3.x, wj[12], s); s = fmaf(c3.y, wj[13], s);
        s = fmaf(c3.z, wj[14], s); s = fmaf(c3.w, wj[15], s);
        out[(size_t)u * 128 + j] = s;
    }
}

extern "C" void kernel_launch(void* const* d_in, const int* in_sizes, int n_in,
                              void* d_out, int out_size, void* d_ws, size_t ws_size,
                              hipStream_t stream)
{
    const float* vf    = (const float*)d_in[0];
    const float* feat2 = (const float*)d_in[1];
    const float* W0    = (const float*)d_in[2];
    const float* g0    = (const float*)d_in[3];
    const float* b0    = (const float*)d_in[4];
    const float* W1    = (const float*)d_in[5];
    const float* g1    = (const float*)d_in[6];
    const float* b1    = (const float*)d_in[7];
    const float* Wobo  = (const float*)d_in[8];
    const float* bobo  = (const float*)d_in[9];
    const float* Wf    = (const float*)d_in[10];
    const float* bf    = (const float*)d_in[11];
    const int*   nbr   = (const int*)d_in[12];
    const int*   seg   = (const int*)d_in[13];

    int N = in_sizes[0] / 16;   // 100000
    int U = out_size / 128;     // num_segments

    float* out = (float*)d_out;
    float* ws  = (float*)d_ws;

    float* y0raw  = ws;                        // N*16
    float* y1raw  = ws + (size_t)N * 16;       // N*16
    float* stats  = ws + (size_t)2 * N * 16;   // 64: stats0[32] | stats1[32]
    float* merged = stats + 64;                // U*16

    hipMemsetAsync(stats, 0, 64 * sizeof(float), stream);
    hipMemsetAsync(merged, 0, (size_t)U * 16 * sizeof(float), stream);

    float invN = 1.f / (float)N;
    int gbC = (N + 127) / 128;        // conv: 128 voxels/block
    int gbN = (N + 255) / 256;
    int n4  = N * 4;

    subm_conv_kernel<false><<<gbC, 256, 0, stream>>>(vf, W0, nbr, nullptr, nullptr,
                                                     nullptr, invN, y0raw, N);
    stats_kernel<<<256, 256, 0, stream>>>(y0raw, stats, n4);
    subm_conv_kernel<true><<<gbC, 256, 0, stream>>>(y0raw, W1, nbr, stats, g0, b0,
                                                    invN, y1raw, N);
    stats_kernel<<<256, 256, 0, stream>>>(y1raw, stats + 32, n4);
    scatter_h_kernel<<<gbN, 256, 0, stream>>>(y1raw, stats + 32, g1, b1, invN,
                                              seg, merged, N);
    scatter_t2_kernel<<<gbN, 256, 0, stream>>>(feat2, Wobo, bobo, seg, merged, N);
    final_gemm_kernel<<<(U + 255) / 256, 256, 0, stream>>>(merged, Wf, bf, out, U);
}

// Round 4
// 194.473 us; speedup vs baseline: 2.0403x; 2.0403x over previous
//
#include <hip/hip_runtime.h>

#define BN_EPS 1e-3f

using bfrag  = __attribute__((ext_vector_type(8))) short;  // 8 bf16 (4 VGPRs)
using f32x4v = __attribute__((ext_vector_type(4))) float;

__device__ __forceinline__ unsigned short f2bf(float f) {
    union { float f; unsigned u; } v; v.f = f;
    unsigned r = v.u + 0x7FFFu + ((v.u >> 16) & 1u);   // RNE
    return (unsigned short)(r >> 16);
}

// ---------------------------------------------------------------------------
// vf [N,16] fp32 -> xb [(N+1),16] bf16, row N = zeros (pad row for missing
// neighbors). Thread handles 8 channels (16B store).
// ---------------------------------------------------------------------------
__global__ __launch_bounds__(256)
void cvt_in_kernel(const float* __restrict__ vf, unsigned short* __restrict__ xb, int N)
{
    int t = blockIdx.x * 256 + threadIdx.x;
    if (t >= (N + 1) * 2) return;
    int n = t >> 1, h = t & 1;
    unsigned short tmp[8];
    if (n < N) {
        const float* yr = vf + (size_t)n * 16 + h * 8;
#pragma unroll
        for (int j = 0; j < 8; ++j) tmp[j] = f2bf(yr[j]);
    } else {
#pragma unroll
        for (int j = 0; j < 8; ++j) tmp[j] = 0;
    }
    *(int4*)(xb + (size_t)n * 16 + h * 8) = *(int4*)tmp;
}

// ---------------------------------------------------------------------------
// Rearrange W [27,16,16] fp32 into MFMA B-fragment order, bf16:
// Wb[s][lane][j] = W[tap][c][n],  tap=2s+(q>>1), c=(q&1)*8+j, n=lane&15,
// q=lane>>4, s=0..13 (tap 27 = zero pad). Both layers in one launch.
// ---------------------------------------------------------------------------
__global__ __launch_bounds__(256)
void wprep_kernel(const float* __restrict__ W0, const float* __restrict__ W1,
                  unsigned short* __restrict__ Wb0, unsigned short* __restrict__ Wb1)
{
    int t = blockIdx.x * 256 + threadIdx.x;
    if (t >= 2 * 14 * 64) return;
    int w = t >= 896;
    int l = t - w * 896;
    int s = l >> 6, lane = l & 63;
    int q = lane >> 4, n = lane & 15;
    int tap = 2 * s + (q >> 1);
    int cb  = (q & 1) * 8;
    const float* W = w ? W1 : W0;
    unsigned short* Wb = w ? Wb1 : Wb0;
    unsigned short tmp[8];
#pragma unroll
    for (int j = 0; j < 8; ++j)
        tmp[j] = (tap < 27) ? f2bf(W[((size_t)(tap * 16 + cb + j)) * 16 + n]) : 0;
    *(int4*)(Wb + (size_t)l * 8) = *(int4*)tmp;
}

// ---------------------------------------------------------------------------
// MFMA submanifold conv: one wave = 16 voxels x 16 outputs, K=432 padded to
// 448 = 14 steps of 16x16x32 bf16. A-frag: lane(q,m) loads 8 bf16 channels
// of x[nbr[m][tap]] (missing -> zero row N). B-frag from pre-swizzled Wb.
// Output y fp32 (pre-BN).
// ---------------------------------------------------------------------------
__global__ __launch_bounds__(256)
void conv_mfma_kernel(const unsigned short* __restrict__ xb,  // [(N+1),16] bf16
                      const unsigned short* __restrict__ Wb,  // [14*64*8] bf16
                      const int* __restrict__ nbr,            // [N,27]
                      float* __restrict__ y, int N)
{
    int gwave = (blockIdx.x * 256 + threadIdx.x) >> 6;
    int lane  = threadIdx.x & 63;
    int base  = gwave * 16;
    if (base >= N) return;
    int q = lane >> 4, m = lane & 15;
    int c0   = (q & 1) * 8;
    int tpar = q >> 1;
    int vox  = base + m;

    const int* nr = nbr + (size_t)vox * 27;
    int idx[14];
#pragma unroll
    for (int s = 0; s < 14; ++s) {
        int tap = 2 * s + tpar;
        int id  = (tap < 27) ? nr[tap] : -1;
        idx[s]  = (id >= 0) ? id : N;     // row N = zeros
    }

    f32x4v acc = {0.f, 0.f, 0.f, 0.f};
#pragma unroll
    for (int s = 0; s < 14; ++s) {
        bfrag a = *(const bfrag*)(xb + (size_t)idx[s] * 16 + c0);
        bfrag b = *(const bfrag*)(Wb + ((size_t)s * 64 + lane) * 8);
        acc = __builtin_amdgcn_mfma_f32_16x16x32_bf16(a, b, acc, 0, 0, 0);
    }

    // C/D: col = lane&15 = output channel, row = q*4+i = voxel-in-tile
    int o = lane & 15;
#pragma unroll
    for (int i = 0; i < 4; ++i)
        y[(size_t)(base + q * 4 + i) * 16 + o] = acc[i];
}

// ---------------------------------------------------------------------------
// Per-channel sum / sumsq over y [N,16].
// ---------------------------------------------------------------------------
__global__ __launch_bounds__(256)
void stats_kernel(const float* __restrict__ y, float* __restrict__ stats, int n4)
{
    __shared__ float red[4][32];
    int tid = blockIdx.x * 256 + threadIdx.x;
    int T = gridDim.x * 256;
    float4 s = make_float4(0.f, 0.f, 0.f, 0.f);
    float4 qq = make_float4(0.f, 0.f, 0.f, 0.f);
    for (int f = tid; f < n4; f += T) {
        float4 v = ((const float4*)y)[f];
        s.x += v.x; s.y += v.y; s.z += v.z; s.w += v.w;
        qq.x += v.x * v.x; qq.y += v.y * v.y; qq.z += v.z * v.z; qq.w += v.w * v.w;
    }
#pragma unroll
    for (int off = 4; off <= 32; off <<= 1) {
        s.x += __shfl_down(s.x, off); s.y += __shfl_down(s.y, off);
        s.z += __shfl_down(s.z, off); s.w += __shfl_down(s.w, off);
        qq.x += __shfl_down(qq.x, off); qq.y += __shfl_down(qq.y, off);
        qq.z += __shfl_down(qq.z, off); qq.w += __shfl_down(qq.w, off);
    }
    int lane = threadIdx.x & 63, wv = threadIdx.x >> 6;
    if (lane < 4) {
        int c = lane * 4;
        red[wv][c + 0] = s.x; red[wv][c + 1] = s.y; red[wv][c + 2] = s.z; red[wv][c + 3] = s.w;
        red[wv][16 + c + 0] = qq.x; red[wv][16 + c + 1] = qq.y;
        red[wv][16 + c + 2] = qq.z; red[wv][16 + c + 3] = qq.w;
    }
    __syncthreads();
    if (threadIdx.x < 32) {
        float v = red[0][threadIdx.x] + red[1][threadIdx.x] +
                  red[2][threadIdx.x] + red[3][threadIdx.x];
        atomicAdd(&stats[threadIdx.x], v);
    }
}

// ---------------------------------------------------------------------------
// xb1[n] = bf16(relu(y0[n]*sc+sh)), row N = zeros. Thread = 8 channels.
// ---------------------------------------------------------------------------
__global__ __launch_bounds__(256)
void bnrelu_cvt_kernel(const float* __restrict__ y0, const float* __restrict__ stats,
                       const float* __restrict__ g, const float* __restrict__ b,
                       float invN, unsigned short* __restrict__ xb, int N)
{
    int t = blockIdx.x * 256 + threadIdx.x;
    if (t >= (N + 1) * 2) return;
    int n = t >> 1, h = t & 1;
    unsigned short tmp[8];
    if (n < N) {
        const float* yr = y0 + (size_t)n * 16 + h * 8;
#pragma unroll
        for (int j = 0; j < 8; ++j) {
            int c = h * 8 + j;
            float mu  = stats[c] * invN;
            float var = stats[16 + c] * invN - mu * mu;
            float sc  = g[c] * rsqrtf(var + BN_EPS);
            float v   = fmaxf(fmaf(yr[j], sc, b[c] - mu * sc), 0.f);
            tmp[j] = f2bf(v);
        }
    } else {
#pragma unroll
        for (int j = 0; j < 8; ++j) tmp[j] = 0;
    }
    *(int4*)(xb + (size_t)n * 16 + h * 8) = *(int4*)tmp;
}

// First tensor: relu(bn1(y1)) -> plain stores (seg[0:N] strictly increasing).
__global__ __launch_bounds__(256)
void scatter_h_kernel(const float* __restrict__ y1, const float* __restrict__ stats,
                      const float* __restrict__ g, const float* __restrict__ b,
                      float invN, const int* __restrict__ seg,
                      float* __restrict__ merged, int N)
{
    int r = blockIdx.x * 256 + threadIdx.x;
    if (r >= N) return;
    float sc[16], sh[16];
#pragma unroll
    for (int c = 0; c < 16; ++c) {
        float mu  = stats[c] * invN;
        float var = stats[16 + c] * invN - mu * mu;
        float s   = g[c] * rsqrtf(var + BN_EPS);
        sc[c] = s;
        sh[c] = b[c] - mu * s;
    }
    const float4* yr = (const float4*)(y1 + (size_t)r * 16);
    float4* mo = (float4*)(merged + (size_t)seg[r] * 16);
#pragma unroll
    for (int i = 0; i < 4; ++i) {
        float4 v = yr[i];
        float4 rr;
        rr.x = fmaxf(fmaf(v.x, sc[i * 4 + 0], sh[i * 4 + 0]), 0.f);
        rr.y = fmaxf(fmaf(v.y, sc[i * 4 + 1], sh[i * 4 + 1]), 0.f);
        rr.z = fmaxf(fmaf(v.z, sc[i * 4 + 2], sh[i * 4 + 2]), 0.f);
        rr.w = fmaxf(fmaf(v.w, sc[i * 4 + 3], sh[i * 4 + 3]), 0.f);
        mo[i] = rr;
    }
}

__device__ __forceinline__ void obo_row(const float* __restrict__ feat2,
                                        const float* __restrict__ Wobo,
                                        int r, float v[16])
{
    const float4* fr = (const float4*)(feat2 + (size_t)r * 16);
    float fv[16];
    *(float4*)(fv + 0)  = fr[0]; *(float4*)(fv + 4)  = fr[1];
    *(float4*)(fv + 8)  = fr[2]; *(float4*)(fv + 12) = fr[3];
#pragma unroll
    for (int c = 0; c < 16; ++c) {
        float xc = fv[c];
        const float* wr = Wobo + c * 16;
#pragma unroll
        for (int o = 0; o < 16; ++o) v[o] = fmaf(xc, wr[o], v[o]);
    }
}

// Second tensor: seg[N:2N] non-decreasing -> equal slots are adjacent runs;
// run leader sums the run, plain load-add-store. No atomics.
__global__ __launch_bounds__(256)
void scatter_t2_kernel(const float* __restrict__ feat2, const float* __restrict__ Wobo,
                       const float* __restrict__ bobo, const int* __restrict__ seg,
                       float* __restrict__ merged, int N)
{
    int r = blockIdx.x * 256 + threadIdx.x;
    if (r >= N) return;
    const int* seg2 = seg + N;
    int s = seg2[r];
    if (r > 0 && seg2[r - 1] == s) return;
    float v[16];
#pragma unroll
    for (int o = 0; o < 16; ++o) v[o] = bobo[o];
    obo_row(feat2, Wobo, r, v);
    for (int i = r + 1; i < N && seg2[i] == s; ++i)
        obo_row(feat2, Wobo, i, v);
    float4* mo4 = (float4*)(merged + (size_t)s * 16);
    float4 m0 = mo4[0], m1 = mo4[1], m2 = mo4[2], m3 = mo4[3];
    mo4[0] = make_float4(m0.x + v[0],  m0.y + v[1],  m0.z + v[2],  m0.w + v[3]);
    mo4[1] = make_float4(m1.x + v[4],  m1.y + v[5],  m1.z + v[6],  m1.w + v[7]);
    mo4[2] = make_float4(m2.x + v[8],  m2.y + v[9],  m2.z + v[10], m2.w + v[11]);
    mo4[3] = make_float4(m3.x + v[12], m3.y + v[13], m3.z + v[14], m3.w + v[15]);
}

// out[u,:] = merged[u,:16] @ Wf + bf. Thread = 4 output cols (jg) x 16 rows;
// Wf column-block in 16 float4 regs; depth-1 row prefetch; float4 stores
// (32 lanes x 16B = 512B contiguous per row).
__global__ __launch_bounds__(256)
void final_gemm_kernel(const float* __restrict__ merged, const float* __restrict__ Wf,
                       const float* __restrict__ bf, float* __restrict__ out, int U)
{
    int jg = threadIdx.x & 31;
    int ub = threadIdx.x >> 5;
    int u0 = (blockIdx.x * 8 + ub) * 16;
    if (u0 >= U) return;
    float4 wf[16];
#pragma unroll
    for (int c = 0; c < 16; ++c) wf[c] = *(const float4*)(Wf + c * 128 + jg * 4);
    float4 bj = *(const float4*)(bf + jg * 4);
    int uend = min(u0 + 16, U);

    const float4* mr = (const float4*)(merged + (size_t)u0 * 16);
    float4 a0 = mr[0], a1 = mr[1], a2 = mr[2], a3 = mr[3];
#pragma unroll 1
    for (int u = u0; u < uend; ++u) {
        float4 c0 = a0, c1 = a1, c2 = a2, c3 = a3;
        if (u + 1 < uend) {
            const float4* nx = (const float4*)(merged + (size_t)(u + 1) * 16);
            a0 = nx[0]; a1 = nx[1]; a2 = nx[2]; a3 = nx[3];
        }
        float m[16];
        *(float4*)(m + 0)  = c0; *(float4*)(m + 4)  = c1;
        *(float4*)(m + 8)  = c2; *(float4*)(m + 12) = c3;
        float4 s = bj;
#pragma unroll
        for (int c = 0; c < 16; ++c) {
            s.x = fmaf(m[c], wf[c].x, s.x);
            s.y = fmaf(m[c], wf[c].y, s.y);
            s.z = fmaf(m[c], wf[c].z, s.z);
            s.w = fmaf(m[c], wf[c].w, s.w);
        }
        *(float4*)(out + (size_t)u * 128 + jg * 4) = s;
    }
}

extern "C" void kernel_launch(void* const* d_in, const int* in_sizes, int n_in,
                              void* d_out, int out_size, void* d_ws, size_t ws_size,
                              hipStream_t stream)
{
    const float* vf    = (const float*)d_in[0];
    const float* feat2 = (const float*)d_in[1];
    const float* W0    = (const float*)d_in[2];
    const float* g0    = (const float*)d_in[3];
    const float* b0    = (const float*)d_in[4];
    const float* W1    = (const float*)d_in[5];
    const float* g1    = (const float*)d_in[6];
    const float* b1    = (const float*)d_in[7];
    const float* Wobo  = (const float*)d_in[8];
    const float* bobo  = (const float*)d_in[9];
    const float* Wf    = (const float*)d_in[10];
    const float* bf    = (const float*)d_in[11];
    const int*   nbr   = (const int*)d_in[12];
    const int*   seg   = (const int*)d_in[13];

    int N = in_sizes[0] / 16;   // 100000
    int U = out_size / 128;     // num_segments

    float* out = (float*)d_out;
    float* ws  = (float*)d_ws;

    // Workspace layout (float units):
    float* y0     = ws;                                   // N*16
    float* y1     = y0 + (size_t)N * 16;                  // N*16
    float* merged = y1 + (size_t)N * 16;                  // U*16
    float* stats  = merged + (size_t)U * 16;              // 64
    unsigned short* xb0 = (unsigned short*)(stats + 64);  // (N+1)*16 bf16
    unsigned short* xb1 = xb0 + (size_t)(N + 1) * 16;     // (N+1)*16 bf16
    unsigned short* Wb0 = xb1 + (size_t)(N + 1) * 16;     // 14*64*8 bf16
    unsigned short* Wb1 = Wb0 + 14 * 64 * 8;              // 14*64*8 bf16

    hipMemsetAsync(stats, 0, 64 * sizeof(float), stream);
    hipMemsetAsync(merged, 0, (size_t)U * 16 * sizeof(float), stream);

    float invN = 1.f / (float)N;
    int thrCvt = (N + 1) * 2;
    int gbCvt  = (thrCvt + 255) / 256;
    int gbConv = ((N + 15) / 16 * 64 + 255) / 256;   // one wave per 16 voxels
    int gbN    = (N + 255) / 256;
    int n4     = N * 4;

    cvt_in_kernel<<<gbCvt, 256, 0, stream>>>(vf, xb0, N);
    wprep_kernel<<<7, 256, 0, stream>>>(W0, W1, Wb0, Wb1);
    conv_mfma_kernel<<<gbConv, 256, 0, stream>>>(xb0, Wb0, nbr, y0, N);
    stats_kernel<<<256, 256, 0, stream>>>(y0, stats, n4);
    bnrelu_cvt_kernel<<<gbCvt, 256, 0, stream>>>(y0, stats, g0, b0, invN, xb1, N);
    conv_mfma_kernel<<<gbConv, 256, 0, stream>>>(xb1, Wb1, nbr, y1, N);
    stats_kernel<<<256, 256, 0, stream>>>(y1, stats + 32, n4);
    scatter_h_kernel<<<gbN, 256, 0, stream>>>(y1, stats + 32, g1, b1, invN, seg, merged, N);
    scatter_t2_kernel<<<gbN, 256, 0, stream>>>(feat2, Wobo, bobo, seg, merged, N);
    final_gemm_kernel<<<(U + 127) / 128, 256, 0, stream>>>(merged, Wf, bf, out, U);
}